// Round 9
// baseline (61.833 us; speedup 1.0000x reference)
//
#include <hip/hip_runtime.h>
#include <hip/hip_bf16.h>

// Problem constants
#define B_    64
#define C_    1280
#define HW_   49
#define A_    40
#define BN    128          // d-tile per block (R1 champion)
#define BK    32           // k-step (R1 champion)
#define NK    (C_/BK)      // 40
#define NTILE (C_/BN)      // 10
#define WLDS_STRIDE 40     // R1's padded LDS k-stride

typedef short bf16x8 __attribute__((ext_vector_type(8)));
typedef short bf16x4 __attribute__((ext_vector_type(4)));
typedef float f32x4  __attribute__((ext_vector_type(4)));

__device__ __forceinline__ float hswish(float x) {
    float t = fminf(fmaxf(x + 3.0f, 0.0f), 6.0f);
    return x * t * (1.0f / 6.0f);
}

__device__ __forceinline__ short f2bf(float f) {
    __hip_bfloat16 h = __float2bfloat16(f);
    return __builtin_bit_cast(short, h);
}

// Kernel 1: R1 pool verbatim — avg pool (7x7) + h_swish + cvt to bf16
__global__ __launch_bounds__(256) void pool_kernel(const float* __restrict__ x,
                                                   __hip_bfloat16* __restrict__ p) {
    int t = blockIdx.x * 256 + threadIdx.x;   // [0, B_*C_), exact
    const float* src = x + (size_t)t * HW_;
    float s = 0.f;
    #pragma unroll
    for (int i = 0; i < HW_; ++i) s += src[i];
    s *= (1.0f / 49.0f);
    p[t] = __float2bfloat16(hswish(s));
}

// Kernel 2: R1 head with ONE change — W staging uses 4x global_load_dwordx4
// per thread (in-register 4x4 transpose) instead of 16 scalar dwords.
// VMEM instructions per thread per k-step: 17 -> 5.
__global__ __launch_bounds__(256) void head_kernel(
    const short* __restrict__ p,     // [64][1280] bf16
    const float* __restrict__ W1,    // [40][1280][1280]  ([a][k][d])
    const float* __restrict__ b1,    // [40][1280]
    const float* __restrict__ W2,    // [40][1280]
    float* __restrict__ part)        // [NTILE][64][40]
{
    __shared__ short w_lds[BN * WLDS_STRIDE];  // transposed tile: [d][k], bf16
    __shared__ short p_lds[B_ * BK];           // [b][k], bf16

    const int tid  = threadIdx.x;
    const int lane = tid & 63;
    const int wid  = tid >> 6;
    const int ntile = blockIdx.x;              // 0..9
    const int a     = blockIdx.y;              // 0..39
    const int n0    = ntile * BN;

    const int l15 = lane & 15;
    const int lg  = lane >> 4;

    // W staging map: thread owns d4 = (tid&31)*4 (4 consecutive d),
    // kg = (tid>>5)*4 (4 consecutive k). Each load j: one float4 = row
    // k0+kg+j, cols d4..d4+3. Wave footprint per load: 2x512B contiguous.
    const int d4 = (tid & 31) * 4;
    const int kg = (tid >> 5) * 4;
    const float* w1base = W1 + (size_t)a * C_ * C_ + (size_t)kg * C_ + n0 + d4;

    // p staging map (R1): row = tid>>2, k-offset = (tid&3)*8 (16B per thread)
    const int prow = tid >> 2;
    const int pkof = (tid & 3) * 8;

    f32x4 acc[8];
    #pragma unroll
    for (int n = 0; n < 8; ++n) acc[n] = (f32x4){0.f, 0.f, 0.f, 0.f};

    float4 wcur[4];    // wcur[j] = W[k0+kg+j][d4 .. d4+3]
    bf16x8 pcur;
    // prologue: issue loads for k-tile 0
    {
        #pragma unroll
        for (int j = 0; j < 4; ++j)
            wcur[j] = *reinterpret_cast<const float4*>(w1base + (size_t)j * C_);
        pcur = *reinterpret_cast<const bf16x8*>(p + prow * C_ + pkof);
    }

    for (int kt = 0; kt < NK; ++kt) {
        __syncthreads();   // previous compute phase done reading LDS

        // in-register 4x4 transpose, write rows d4..d4+3 at col kg (b64 each)
        #pragma unroll
        for (int i = 0; i < 4; ++i) {
            bf16x4 v;
            v[0] = f2bf(wcur[0][i]);
            v[1] = f2bf(wcur[1][i]);
            v[2] = f2bf(wcur[2][i]);
            v[3] = f2bf(wcur[3][i]);
            *reinterpret_cast<bf16x4*>(&w_lds[(d4 + i) * WLDS_STRIDE + kg]) = v;
        }
        *reinterpret_cast<bf16x8*>(&p_lds[prow * BK + pkof]) = pcur;

        __syncthreads();

        // issue-early prefetch of next k-tile (in flight across MFMA phase)
        float4 wnxt[4];
        bf16x8 pnxt;
        if (kt + 1 < NK) {
            const float* wb = w1base + (size_t)(kt + 1) * BK * C_;
            #pragma unroll
            for (int j = 0; j < 4; ++j)
                wnxt[j] = *reinterpret_cast<const float4*>(wb + (size_t)j * C_);
            pnxt = *reinterpret_cast<const bf16x8*>(p + prow * C_ + (kt + 1) * BK + pkof);
        }

        // compute: wave wid owns rows [wid*16, wid*16+16)
        bf16x8 afrag = *reinterpret_cast<const bf16x8*>(&p_lds[(wid * 16 + l15) * BK + lg * 8]);
        #pragma unroll
        for (int n = 0; n < 8; ++n) {
            bf16x8 bfrag = *reinterpret_cast<const bf16x8*>(
                &w_lds[(n * 16 + l15) * WLDS_STRIDE + lg * 8]);
            acc[n] = __builtin_amdgcn_mfma_f32_16x16x32_bf16(afrag, bfrag, acc[n], 0, 0, 0);
        }

        #pragma unroll
        for (int j = 0; j < 4; ++j) wcur[j] = wnxt[j];
        pcur = pnxt;
    }

    // epilogue (R1 verbatim): h_swish(acc + b1) . W2, reduce over d
    float partial[4] = {0.f, 0.f, 0.f, 0.f};
    #pragma unroll
    for (int n = 0; n < 8; ++n) {
        int d = n0 + n * 16 + l15;
        float b1v = b1[a * C_ + d];
        float w2v = W2[a * C_ + d];
        #pragma unroll
        for (int r = 0; r < 4; ++r) {
            float h = hswish(acc[n][r] + b1v);
            partial[r] += h * w2v;
        }
    }
    #pragma unroll
    for (int off = 8; off >= 1; off >>= 1) {
        #pragma unroll
        for (int r = 0; r < 4; ++r)
            partial[r] += __shfl_xor(partial[r], off, 64);
    }
    if (l15 == 0) {
        int brow = wid * 16 + lg * 4;   // C/D layout: row=(lane>>4)*4+r, col=lane&15
        #pragma unroll
        for (int r = 0; r < 4; ++r)
            part[ntile * (B_ * A_) + (brow + r) * A_ + a] = partial[r];
    }
}

// Kernel 3: sum partials over the 10 d-tiles, add b2, sigmoid
__global__ __launch_bounds__(256) void fin_kernel(const float* __restrict__ part,
                                                  const float* __restrict__ b2,
                                                  float* __restrict__ out) {
    int idx = blockIdx.x * 256 + threadIdx.x;
    if (idx >= B_ * A_) return;
    int a = idx % A_;
    float s = b2[a];
    #pragma unroll
    for (int nb = 0; nb < NTILE; ++nb) s += part[nb * (B_ * A_) + idx];
    out[idx] = 1.0f / (1.0f + expf(-s));
}

extern "C" void kernel_launch(void* const* d_in, const int* in_sizes, int n_in,
                              void* d_out, int out_size, void* d_ws, size_t ws_size,
                              hipStream_t stream) {
    const float* x  = (const float*)d_in[0];
    const float* W1 = (const float*)d_in[1];
    const float* b1 = (const float*)d_in[2];
    const float* W2 = (const float*)d_in[3];
    const float* b2 = (const float*)d_in[4];
    float* out = (float*)d_out;

    __hip_bfloat16* p = (__hip_bfloat16*)d_ws;                      // 160 KB
    float* part = (float*)((char*)d_ws + (size_t)B_ * C_ * 2);      // 100 KB

    pool_kernel<<<(B_ * C_) / 256, 256, 0, stream>>>(x, p);
    head_kernel<<<dim3(NTILE, A_), 256, 0, stream>>>((const short*)p, W1, b1, W2, part);
    fin_kernel<<<(B_ * A_ + 255) / 256, 256, 0, stream>>>(part, b2, out);
}